// Round 6
// baseline (9433.266 us; speedup 1.0000x reference)
//
#include <hip/hip_runtime.h>
#include <math.h>

typedef unsigned short u16;
typedef __attribute__((ext_vector_type(8))) short short8;
typedef __attribute__((ext_vector_type(8))) _Float16 half8;
typedef __attribute__((ext_vector_type(4))) float floatx4;

#define NH 16
#define NKV 8
#define HD 256
#define SEQ 2048
#define BATCH 2
#define QD (NH * HD)    // 4096
#define KVD (NKV * HD)  // 2048
#define WINDOW 1024

__device__ __forceinline__ u16 f2h(float f) {
    _Float16 h = (_Float16)f;
    return __builtin_bit_cast(u16, h);
}
__device__ __forceinline__ float h2f(u16 u) {
    return (float)__builtin_bit_cast(_Float16, u);
}

// load 8 contiguous elements as f16 bits (converting from f32 if F32)
template<bool F32>
__device__ __forceinline__ short8 load8(const void* p, size_t idx) {
    if constexpr (F32) {
        const float* f = (const float*)p + idx;
        float4 a = *(const float4*)(f);
        float4 b = *(const float4*)(f + 4);
        short8 r;
        r[0] = (short)f2h(a.x); r[1] = (short)f2h(a.y);
        r[2] = (short)f2h(a.z); r[3] = (short)f2h(a.w);
        r[4] = (short)f2h(b.x); r[5] = (short)f2h(b.y);
        r[6] = (short)f2h(b.z); r[7] = (short)f2h(b.w);
        return r;
    } else {
        return *(const short8*)((const u16*)p + idx);
    }
}

// ---------------------------------------------------------------------------
// GEMM: C[M,N] = A[M,K] * B[N,K]^T, fp32 accum, f16 MFMA internally.
// A/B f32 (converted on stage) or f16-bits; C written f32 (OUTF32) or f16.
// 128x128 tile, BK=32, 256 threads = 4 waves, each wave 64x64 (4x4 MFMA).
// ---------------------------------------------------------------------------
template<bool AF32, bool BF32, bool OUTF32>
__global__ __launch_bounds__(256) void gemm_bt(const void* __restrict__ Ap,
                                               const void* __restrict__ Bp,
                                               void* __restrict__ Cp,
                                               int M, int N, int K) {
    constexpr int LDA = 40;  // 32 + 8 pad; row stride 80B, 16B aligned
    __shared__ u16 As[128 * LDA];
    __shared__ u16 Bs[128 * LDA];

    const int tid = threadIdx.x;
    const int wave = tid >> 6, lane = tid & 63;
    const int quad = lane >> 4, l16 = lane & 15;
    const int bm = blockIdx.y * 128, bn = blockIdx.x * 128;
    const int wm = (wave >> 1) * 64, wn = (wave & 1) * 64;
    const int srow = tid >> 2;          // 0..63
    const int scol = (tid & 3) * 8;     // 0,8,16,24

    floatx4 acc[4][4];
#pragma unroll
    for (int i = 0; i < 4; ++i)
#pragma unroll
        for (int j = 0; j < 4; ++j) acc[i][j] = (floatx4){0.f, 0.f, 0.f, 0.f};

    const int kTiles = K >> 5;
    for (int kt = 0; kt < kTiles; ++kt) {
        const int k0 = kt << 5;
        short8 a0 = load8<AF32>(Ap, (size_t)(bm + srow) * K + k0 + scol);
        short8 a1 = load8<AF32>(Ap, (size_t)(bm + 64 + srow) * K + k0 + scol);
        short8 b0 = load8<BF32>(Bp, (size_t)(bn + srow) * K + k0 + scol);
        short8 b1 = load8<BF32>(Bp, (size_t)(bn + 64 + srow) * K + k0 + scol);
        __syncthreads();  // previous iteration's LDS reads complete
        *(short8*)(&As[srow * LDA + scol]) = a0;
        *(short8*)(&As[(64 + srow) * LDA + scol]) = a1;
        *(short8*)(&Bs[srow * LDA + scol]) = b0;
        *(short8*)(&Bs[(64 + srow) * LDA + scol]) = b1;
        __syncthreads();

        half8 af[4], bfr[4];
#pragma unroll
        for (int i = 0; i < 4; ++i)
            af[i] = *(const half8*)(&As[(wm + i * 16 + l16) * LDA + quad * 8]);
#pragma unroll
        for (int j = 0; j < 4; ++j)
            bfr[j] = *(const half8*)(&Bs[(wn + j * 16 + l16) * LDA + quad * 8]);
#pragma unroll
        for (int i = 0; i < 4; ++i)
#pragma unroll
            for (int j = 0; j < 4; ++j)
                acc[i][j] = __builtin_amdgcn_mfma_f32_16x16x32_f16(af[i], bfr[j], acc[i][j], 0, 0, 0);
    }

    // epilogue: C row = bm+wm+i*16+quad*4+r, col = bn+wn+j*16+l16
#pragma unroll
    for (int i = 0; i < 4; ++i) {
#pragma unroll
        for (int j = 0; j < 4; ++j) {
            const int row0 = bm + wm + i * 16 + quad * 4;
            const int col = bn + wn + j * 16 + l16;
#pragma unroll
            for (int r = 0; r < 4; ++r) {
                if constexpr (OUTF32)
                    ((float*)Cp)[(size_t)(row0 + r) * N + col] = acc[i][j][r];
                else
                    ((u16*)Cp)[(size_t)(row0 + r) * N + col] = f2h(acc[i][j][r]);
            }
        }
    }
}

// ---------------------------------------------------------------------------
// Fused per-head RMSNorm (+weight) and RoPE. One wave per (row, head-slot).
// slots: 0..15 Q heads, 16..23 K heads, 24..31 V heads. In-place on ws (f16).
// qw/kw/cos/sin are f32.
// ---------------------------------------------------------------------------
__global__ __launch_bounds__(256) void norm_rope_kernel(
        u16* __restrict__ Q, u16* __restrict__ K, u16* __restrict__ V,
        const float* __restrict__ qw, const float* __restrict__ kw,
        const float* __restrict__ cosp, const float* __restrict__ sinp) {
    const int w = blockIdx.x * 4 + (threadIdx.x >> 6);
    const int lane = threadIdx.x & 63;
    const int row = w >> 5;   // 0..4095 (= b*2048+s)
    const int sub = w & 31;

    u16* ptr;
    const float* wt;
    bool dorope;
    if (sub < 16)      { ptr = Q + (size_t)row * QD + sub * HD;         wt = qw;      dorope = true;  }
    else if (sub < 24) { ptr = K + (size_t)row * KVD + (sub - 16) * HD; wt = kw;      dorope = true;  }
    else               { ptr = V + (size_t)row * KVD + (sub - 24) * HD; wt = nullptr; dorope = false; }

    const int d = lane * 4;
    uint2 raw = *(const uint2*)(ptr + d);
    float x[4];
    x[0] = h2f((u16)(raw.x & 0xffffu));
    x[1] = h2f((u16)(raw.x >> 16));
    x[2] = h2f((u16)(raw.y & 0xffffu));
    x[3] = h2f((u16)(raw.y >> 16));

    float ss = x[0] * x[0] + x[1] * x[1] + x[2] * x[2] + x[3] * x[3];
#pragma unroll
    for (int m = 1; m < 64; m <<= 1) ss += __shfl_xor(ss, m, 64);
    const float sc = rsqrtf(ss * (1.0f / 256.0f) + 1e-6f);

    float wv[4];
    if (wt) {
#pragma unroll
        for (int i = 0; i < 4; ++i) wv[i] = wt[d + i];
    } else {
#pragma unroll
        for (int i = 0; i < 4; ++i) wv[i] = 1.0f;
    }
    float nrm[4];
#pragma unroll
    for (int i = 0; i < 4; ++i) nrm[i] = x[i] * sc * wv[i];

    float out[4];
    if (dorope) {
        const size_t cbase = (size_t)row * HD + d;
        const float sgn = (lane < 32) ? -1.0f : 1.0f;
#pragma unroll
        for (int i = 0; i < 4; ++i) {
            float pn = __shfl_xor(nrm[i], 32, 64);  // partner holds d±128
            float c = cosp[cbase + i];
            float s = sinp[cbase + i];
            out[i] = nrm[i] * c + sgn * pn * s;
        }
    } else {
#pragma unroll
        for (int i = 0; i < 4; ++i) out[i] = nrm[i];
    }

    uint2 o;
    o.x = (unsigned int)f2h(out[0]) | ((unsigned int)f2h(out[1]) << 16);
    o.y = (unsigned int)f2h(out[2]) | ((unsigned int)f2h(out[3]) << 16);
    *(uint2*)(ptr + d) = o;
}

// ---------------------------------------------------------------------------
// Brute-force sliding-window attention (kept until pass established).
// One block (256 thr) per (b, h, qi). All storage f16, math f32.
// ---------------------------------------------------------------------------
__global__ __launch_bounds__(256) void attn_brute(
        const u16* __restrict__ Q, const u16* __restrict__ K,
        const u16* __restrict__ V, u16* __restrict__ O) {
    __shared__ float qs[HD];
    __shared__ float ps[WINDOW];
    __shared__ float redm[4];
    __shared__ float reds[4];

    const int tid = threadIdx.x;
    const int wave = tid >> 6, lane = tid & 63;
    const int qi = blockIdx.x, h = blockIdx.y, b = blockIdx.z;
    const int kvh = h >> 1;  // jnp.repeat(k, 2, axis=2): new head h -> old h/2

    // stage q row (rmsnorm+rope already applied, f16) as f32
    qs[tid] = h2f(Q[(size_t)(b * SEQ + qi) * QD + h * HD + tid]);
    __syncthreads();

    int lo = qi - (WINDOW - 1);
    if (lo < 0) lo = 0;
    const int nk = qi - lo + 1;  // valid keys: (key<=qi)&(qi-key<WINDOW)

    // phase 1: raw scores (reference has no 1/sqrt(d) scale)
    for (int kk = tid; kk < nk; kk += 256) {
        const u16* kp = K + (size_t)(b * SEQ + lo + kk) * KVD + kvh * HD;
        float s = 0.f;
        for (int d = 0; d < HD; d += 8) {
            short8 k8 = *(const short8*)(kp + d);
#pragma unroll
            for (int j = 0; j < 8; ++j) s += qs[d + j] * h2f((u16)k8[j]);
        }
        ps[kk] = s;
    }
    __syncthreads();

    // phase 2a: block max
    float mx = -INFINITY;
    for (int kk = tid; kk < nk; kk += 256) mx = fmaxf(mx, ps[kk]);
#pragma unroll
    for (int m = 1; m < 64; m <<= 1) mx = fmaxf(mx, __shfl_xor(mx, m, 64));
    if (lane == 0) redm[wave] = mx;
    __syncthreads();
    mx = fmaxf(fmaxf(redm[0], redm[1]), fmaxf(redm[2], redm[3]));

    // phase 2b: exp + block sum
    float sum = 0.f;
    for (int kk = tid; kk < nk; kk += 256) {
        float p = __expf(ps[kk] - mx);
        ps[kk] = p;
        sum += p;
    }
#pragma unroll
    for (int m = 1; m < 64; m <<= 1) sum += __shfl_xor(sum, m, 64);
    if (lane == 0) reds[wave] = sum;
    __syncthreads();  // also guards ps[] updates before phase 3
    const float inv = 1.0f / (reds[0] + reds[1] + reds[2] + reds[3]);

    // phase 3: out[d] = sum_k p[k] * v[k][d]; thread = dim d -> coalesced
    float acc = 0.f;
    const u16* vp = V + (size_t)(b * SEQ + lo) * KVD + kvh * HD + tid;
    for (int kk = 0; kk < nk; ++kk) acc += ps[kk] * h2f(vp[(size_t)kk * KVD]);

    O[(size_t)(b * SEQ + qi) * QD + h * HD + tid] = f2h(acc * inv);
}

// ---------------------------------------------------------------------------
extern "C" void kernel_launch(void* const* d_in, const int* in_sizes, int n_in,
                              void* d_out, int out_size, void* d_ws, size_t ws_size,
                              hipStream_t stream) {
    const void*  X    = d_in[0];                 // hidden_states (2,2048,2816) f32
    const void*  Wq   = d_in[1];                 // (4096,2816) f32
    const void*  Wk   = d_in[2];                 // (2048,2816) f32
    const void*  Wv   = d_in[3];                 // (2048,2816) f32
    const void*  Wo   = d_in[4];                 // (2816,4096) f32
    const float* qw   = (const float*)d_in[5];   // (256,) f32
    const float* kw   = (const float*)d_in[6];   // (256,) f32
    const float* cosp = (const float*)d_in[7];   // (2,2048,256) f32
    const float* sinp = (const float*)d_in[8];   // (2,2048,256) f32

    char* ws = (char*)d_ws;
    u16* Qb = (u16*)(ws);                    // 4096x4096 f16 = 32 MB
    u16* Kb = (u16*)(ws + (size_t)33554432); // 4096x2048 f16 = 16 MB
    u16* Vb = (u16*)(ws + (size_t)50331648); // 4096x2048 f16 = 16 MB
    u16* Ob = (u16*)(ws + (size_t)67108864); // 4096x4096 f16 = 32 MB

    const dim3 blk(256);
    gemm_bt<true, true, false><<<dim3(4096 / 128, 4096 / 128), blk, 0, stream>>>(X, Wq, Qb, 4096, 4096, 2816);
    gemm_bt<true, true, false><<<dim3(2048 / 128, 4096 / 128), blk, 0, stream>>>(X, Wk, Kb, 4096, 2048, 2816);
    gemm_bt<true, true, false><<<dim3(2048 / 128, 4096 / 128), blk, 0, stream>>>(X, Wv, Vb, 4096, 2048, 2816);
    norm_rope_kernel<<<dim3((BATCH * SEQ * 32) / 4), blk, 0, stream>>>(Qb, Kb, Vb, qw, kw, cosp, sinp);
    attn_brute<<<dim3(SEQ, NH, BATCH), blk, 0, stream>>>(Qb, Kb, Vb, Ob);
    gemm_bt<false, true, true><<<dim3(2816 / 128, 4096 / 128), blk, 0, stream>>>(Ob, Wo, d_out, 4096, 2816, 4096);
}